// Round 4
// baseline (695.007 us; speedup 1.0000x reference)
//
#include <hip/hip_runtime.h>

#define IN_DIM 512
#define BATCH  512
#define NCLS   100000
#define NCPAD  100096   // padded column count (782*128)
#define NC     10
#define NTILE  782      // 128-column tiles per row

using half8_t  = __attribute__((ext_vector_type(8))) _Float16;
using ushort8  = __attribute__((ext_vector_type(8))) unsigned short;
using floatx4  = __attribute__((ext_vector_type(4))) float;

// ---------------------------------------------------------------------------
// K1: row norms of x, f16 hi/lo split (x scaled by 16), y-dtype detection
//     (round-2 proven numerics)
// ---------------------------------------------------------------------------
__global__ __launch_bounds__(256) void k_prep(const float* __restrict__ x,
                                              const int* __restrict__ yraw,
                                              _Float16* __restrict__ xhi,
                                              _Float16* __restrict__ xlo,
                                              float* __restrict__ invx,
                                              int* __restrict__ yflag) {
  int b = blockIdx.x, t = threadIdx.x;
  __shared__ float red[256];
  float v0 = x[b * IN_DIM + t];
  float v1 = x[b * IN_DIM + t + 256];
  red[t] = v0 * v0 + v1 * v1;
  __syncthreads();
  for (int s = 128; s > 0; s >>= 1) {
    if (t < s) red[t] += red[t + s];
    __syncthreads();
  }
  if (t == 0) invx[b] = 1.0f / fmaxf(sqrtf(red[0]), 1e-12f);

  float s0 = v0 * 16.f, s1 = v1 * 16.f;
  _Float16 h0 = (_Float16)s0, h1 = (_Float16)s1;
  xhi[b * IN_DIM + t]       = h0;
  xhi[b * IN_DIM + t + 256] = h1;
  xlo[b * IN_DIM + t]       = (_Float16)(s0 - (float)h0);
  xlo[b * IN_DIM + t + 256] = (_Float16)(s1 - (float)h1);

  if (b == 0 && t == 0) {
    // int64 little-endian layout => every odd 32-bit word is 0
    int allz = 1;
    for (int i = 1; i < 512; i += 2) allz &= (yraw[i] == 0);
    *yflag = allz;
  }
}

// ---------------------------------------------------------------------------
// K1b: one-time W split. W[k][c] fp32 -> WhiT/WloT f16 planes in TRANSPOSED
//      [c][k] layout (contiguous per-column k-runs for copy-only GEMM
//      staging), plus per-column inv-norm (with the 1/4096 scale fold).
//      hi/lo formula is bit-identical to the round-2 in-GEMM conversion.
// ---------------------------------------------------------------------------
__global__ __launch_bounds__(256) void k_wsplit(const float* __restrict__ W,
                                                unsigned short* __restrict__ WhiT,
                                                unsigned short* __restrict__ WloT,
                                                float* __restrict__ invwG) {
  __shared__ unsigned short sHi[64][72];   // pitch 72 (144B, 16B-aligned rows)
  __shared__ unsigned short sLo[64][72];
  __shared__ float ssred[256];
  const int t    = threadIdx.x;
  const int c0   = blockIdx.x * 64;
  const int lane = t & 63;   // local column
  const int grp  = t >> 6;   // k row-group 0..3
  const int c    = c0 + lane;
  float ss = 0.f;

  for (int kb = 0; kb < 8; kb++) {
#pragma unroll
    for (int it = 0; it < 16; it++) {
      int kl = grp * 16 + it;              // 0..63
      int k  = kb * 64 + kl;
      float w = (c < NCLS) ? W[(size_t)k * NCLS + c] : 0.f;
      ss += w * w;
      float sw = w * 256.f;
      _Float16 h = (_Float16)sw;
      _Float16 l = (_Float16)(sw - (float)h);
      sHi[lane][kl] = __builtin_bit_cast(unsigned short, h);
      sLo[lane][kl] = __builtin_bit_cast(unsigned short, l);
    }
    __syncthreads();
    // write out: 64 cols x 8 chunks of 16B = 512 chunks / 256 threads
#pragma unroll
    for (int q = 0; q < 2; q++) {
      int v = t + q * 256;
      int col = v >> 3, s = v & 7;
      ushort8 hv = *(const ushort8*)&sHi[col][s * 8];
      ushort8 lv = *(const ushort8*)&sLo[col][s * 8];
      size_t o = (size_t)(c0 + col) * IN_DIM + kb * 64 + s * 8;
      *(ushort8*)(WhiT + o) = hv;
      *(ushort8*)(WloT + o) = lv;
    }
    __syncthreads();
  }
  ssred[t] = ss;
  __syncthreads();
  if (t < 64) {
    float tot = ssred[t] + ssred[t + 64] + ssred[t + 128] + ssred[t + 192];
    invwG[c0 + t] = (1.0f / 4096.0f) / fmaxf(sqrtf(tot), 1e-12f);
  }
}

// ---------------------------------------------------------------------------
// K2 (fast): copy-only staging MFMA GEMM. 128x128 tiles, BK=32.
//     All conversion hoisted to k_wsplit -> inner loop is global->LDS copy +
//     ds_read_b128 + 48 MFMA. B LDS padded [col][4+1] -> 2-way read banks.
//     XCD-chunked swizzle kept (FETCH 406->118 MB measured).
// ---------------------------------------------------------------------------
__global__ __launch_bounds__(256, 2) void k_gemm_fast(
    const _Float16* __restrict__ xhi, const _Float16* __restrict__ xlo,
    const unsigned short* __restrict__ WhiT, const unsigned short* __restrict__ WloT,
    const float* __restrict__ invx, const float* __restrict__ invwG,
    const int* __restrict__ yraw, const int* __restrict__ yflag,
    float* __restrict__ tilemax, float* __restrict__ out) {
  __shared__ half8_t lAhi[512], lAlo[512];   // 8KB each, [ko][m]
  __shared__ ushort8 lBhi[640], lBlo[640];   // 10KB each, [col][5] (4 + 1 pad)
  __shared__ float   rred[256];
  __shared__ float   invwn[128];
  __shared__ int     clsb[128];

  const int t = threadIdx.x;
  const int bid = blockIdx.x;
  const int g2  = (bid & 7) * 391 + (bid >> 3);
  const int ct  = g2 >> 2;
  const int m0  = (g2 & 3) * 128;
  const int c0  = ct * 128;

  const int w  = t >> 6;
  const int ll = t & 63;
  const int wm = ((w >> 1) & 1) * 64;
  const int wn = (w & 1) * 64;
  const int ko = ll >> 4, lm = ll & 15;

  if (t < 128) {
    int cg = c0 + t;
    invwn[t] = (cg < NCLS) ? invwG[cg] : 0.f;
    clsb[t]  = (*yflag) ? yraw[2 * (m0 + t)] : yraw[m0 + t];
  }

  floatx4 acc[4][4] = {};

  for (int ks = 0; ks < 16; ks++) {
    const int k0 = ks * 32;
    // ---- A staging (round-2 proven pattern) ----
#pragma unroll
    for (int h = 0; h < 2; h++) {
      int p  = t + h * 256;
      int pk = p >> 7, pm = p & 127;
      size_t off = (size_t)(m0 + pm) * IN_DIM + (size_t)(k0 + pk * 8);
      lAhi[p] = *(const half8_t*)(xhi + off);
      lAlo[p] = *(const half8_t*)(xlo + off);
    }
    // ---- B staging: pure 16B copies from pre-split transposed planes ----
#pragma unroll
    for (int q = 0; q < 2; q++) {
      int u = t + q * 256;
      int col = u >> 2, ch = u & 3;
      size_t boff = (size_t)(c0 + col) * IN_DIM + (size_t)(k0 + ch * 8);
      lBhi[col * 5 + ch] = *(const ushort8*)(WhiT + boff);
      lBlo[col * 5 + ch] = *(const ushort8*)(WloT + boff);
    }
    __syncthreads();

    // ---- fragments + 3-pass MFMA ----
    half8_t ah[4], al[4], bh[4], bl[4];
#pragma unroll
    for (int i = 0; i < 4; i++) {
      int am = wm + i * 16 + lm;
      ah[i] = lAhi[ko * 128 + am];
      al[i] = lAlo[ko * 128 + am];
      int cl = wn + i * 16 + lm;
      bh[i] = __builtin_bit_cast(half8_t, lBhi[cl * 5 + ko]);
      bl[i] = __builtin_bit_cast(half8_t, lBlo[cl * 5 + ko]);
    }
#pragma unroll
    for (int i = 0; i < 4; i++)
#pragma unroll
      for (int j = 0; j < 4; j++) {
        acc[i][j] = __builtin_amdgcn_mfma_f32_16x16x32_f16(ah[i], bh[j], acc[i][j], 0, 0, 0);
        acc[i][j] = __builtin_amdgcn_mfma_f32_16x16x32_f16(ah[i], bl[j], acc[i][j], 0, 0, 0);
        acc[i][j] = __builtin_amdgcn_mfma_f32_16x16x32_f16(al[i], bh[j], acc[i][j], 0, 0, 0);
      }
    __syncthreads();
  }

  // ---- epilogue: C write + per-row tile max (excluding class y) ----
  float rmax[4][4];
#pragma unroll
  for (int i = 0; i < 4; i++)
#pragma unroll
    for (int rr = 0; rr < 4; rr++) rmax[i][rr] = -3.402823466e38f;

#pragma unroll
  for (int i = 0; i < 4; i++) {
#pragma unroll
    for (int rr = 0; rr < 4; rr++) {
      int rl = wm + i * 16 + ko * 4 + rr;   // C/D layout: col=lane&15, row=(lane>>4)*4+reg
      int rg = m0 + rl;
      float ix = invx[rg];
      int mycls = clsb[rl];
#pragma unroll
      for (int j = 0; j < 4; j++) {
        int cl = wn + j * 16 + lm;
        int cg = c0 + cl;
        if (cg < NCLS) {
          float v = acc[i][j][rr] * ix * invwn[cl];
          v = fminf(fmaxf(v, -1.f), 1.f) * 64.f;
          out[(size_t)rg * NCLS + cg] = v;
          if (cg != mycls) rmax[i][rr] = fmaxf(rmax[i][rr], v);
        }
      }
    }
  }
#pragma unroll
  for (int i = 0; i < 4; i++)
#pragma unroll
    for (int rr = 0; rr < 4; rr++) {
#pragma unroll
      for (int off = 1; off < 16; off <<= 1)
        rmax[i][rr] = fmaxf(rmax[i][rr], __shfl_xor(rmax[i][rr], off));
    }
  if (lm == 0) {
#pragma unroll
    for (int i = 0; i < 4; i++)
#pragma unroll
      for (int rr = 0; rr < 4; rr++)
        rred[(wm + i * 16 + ko * 4 + rr) * 2 + (w & 1)] = rmax[i][rr];
  }
  __syncthreads();
  if (t < 128)
    tilemax[(size_t)ct * BATCH + m0 + t] = fmaxf(rred[t * 2], rred[t * 2 + 1]);
}

// ---------------------------------------------------------------------------
// K2 (fallback, small-workspace): exact round-2 GEMM with in-kernel f16 split
// ---------------------------------------------------------------------------
__global__ __launch_bounds__(256, 2) void k_gemm_fb(const _Float16* __restrict__ xhi,
                                                    const _Float16* __restrict__ xlo,
                                                    const float* __restrict__ W,
                                                    const float* __restrict__ invx,
                                                    const int* __restrict__ yraw,
                                                    const int* __restrict__ yflag,
                                                    float* __restrict__ tilemax,
                                                    float* __restrict__ out) {
  __shared__ half8_t lAhi[512], lAlo[512], lBhi[512], lBlo[512];
  __shared__ float   ssred[512];
  __shared__ float   invwn[128];
  __shared__ int     clsb[128];

  const int t = threadIdx.x;
  const int bid = blockIdx.x;
  const int g2  = (bid & 7) * 391 + (bid >> 3);
  const int ct  = g2 >> 2;
  const int m0  = (g2 & 3) * 128;
  const int c0  = ct * 128;

  const int g    = t >> 6;
  const int lane = t & 63;
  const int cpl  = lane * 2;
  const bool cval = (c0 + cpl) < NCLS;

  const int w  = t >> 6;
  const int ll = t & 63;
  const int wm = ((w >> 1) & 1) * 64;
  const int wn = (w & 1) * 64;
  const int ko = ll >> 4, lm = ll & 15;

  if (t < 128) clsb[t] = (*yflag) ? yraw[2 * (m0 + t)] : yraw[m0 + t];

  floatx4 acc[4][4] = {};
  float ss0 = 0.f, ss1 = 0.f;

  for (int ks = 0; ks < 16; ks++) {
    const int k0 = ks * 32;
#pragma unroll
    for (int h = 0; h < 2; h++) {
      int p  = t + h * 256;
      int pk = p >> 7, pm = p & 127;
      size_t off = (size_t)(m0 + pm) * IN_DIM + (size_t)(k0 + pk * 8);
      lAhi[p] = *(const half8_t*)(xhi + off);
      lAlo[p] = *(const half8_t*)(xlo + off);
    }
    half8_t b0h, b0l, b1h, b1l;
#pragma unroll
    for (int r = 0; r < 8; r++) {
      float w0 = 0.f, w1 = 0.f;
      if (cval) {
        const float2 wv = *(const float2*)(W + (size_t)(k0 + g * 8 + r) * NCLS + (c0 + cpl));
        w0 = wv.x; w1 = wv.y;
      }
      ss0 += w0 * w0;
      ss1 += w1 * w1;
      float sw0 = w0 * 256.f, sw1 = w1 * 256.f;
      _Float16 h0 = (_Float16)sw0, h1 = (_Float16)sw1;
      b0h[r] = h0; b1h[r] = h1;
      b0l[r] = (_Float16)(sw0 - (float)h0);
      b1l[r] = (_Float16)(sw1 - (float)h1);
    }
    {
      int bi0 = g * 128 + (cpl >> 1);
      lBhi[bi0] = b0h; lBhi[bi0 + 64] = b1h;
      lBlo[bi0] = b0l; lBlo[bi0 + 64] = b1l;
    }
    __syncthreads();

    half8_t ah[4], al[4], bh[4], bl[4];
#pragma unroll
    for (int i = 0; i < 4; i++) {
      int am = wm + i * 16 + lm;
      ah[i] = lAhi[ko * 128 + am];
      al[i] = lAlo[ko * 128 + am];
      int cl = wn + i * 16 + lm;
      int bidx = ko * 128 + ((cl & 1) << 6) + (cl >> 1);
      bh[i] = lBhi[bidx];
      bl[i] = lBlo[bidx];
    }
#pragma unroll
    for (int i = 0; i < 4; i++)
#pragma unroll
      for (int j = 0; j < 4; j++) {
        acc[i][j] = __builtin_amdgcn_mfma_f32_16x16x32_f16(ah[i], bh[j], acc[i][j], 0, 0, 0);
        acc[i][j] = __builtin_amdgcn_mfma_f32_16x16x32_f16(ah[i], bl[j], acc[i][j], 0, 0, 0);
        acc[i][j] = __builtin_amdgcn_mfma_f32_16x16x32_f16(al[i], bh[j], acc[i][j], 0, 0, 0);
      }
    __syncthreads();
  }

  ssred[cpl * 4 + g]       = ss0;
  ssred[(cpl + 1) * 4 + g] = ss1;
  __syncthreads();
  if (t < 128) {
    float s = ssred[t * 4] + ssred[t * 4 + 1] + ssred[t * 4 + 2] + ssred[t * 4 + 3];
    invwn[t] = (1.0f / 4096.0f) / fmaxf(sqrtf(s), 1e-12f);
  }
  __syncthreads();

  float rmax[4][4];
#pragma unroll
  for (int i = 0; i < 4; i++)
#pragma unroll
    for (int rr = 0; rr < 4; rr++) rmax[i][rr] = -3.402823466e38f;

#pragma unroll
  for (int i = 0; i < 4; i++) {
#pragma unroll
    for (int rr = 0; rr < 4; rr++) {
      int rl = wm + i * 16 + ko * 4 + rr;
      int rg = m0 + rl;
      float ix = invx[rg];
      int mycls = clsb[rl];
#pragma unroll
      for (int j = 0; j < 4; j++) {
        int cl = wn + j * 16 + lm;
        int cg = c0 + cl;
        if (cg < NCLS) {
          float v = acc[i][j][rr] * ix * invwn[cl];
          v = fminf(fmaxf(v, -1.f), 1.f) * 64.f;
          out[(size_t)rg * NCLS + cg] = v;
          if (cg != mycls) rmax[i][rr] = fmaxf(rmax[i][rr], v);
        }
      }
    }
  }
#pragma unroll
  for (int i = 0; i < 4; i++)
#pragma unroll
    for (int rr = 0; rr < 4; rr++) {
#pragma unroll
      for (int off = 1; off < 16; off <<= 1)
        rmax[i][rr] = fmaxf(rmax[i][rr], __shfl_xor(rmax[i][rr], off));
    }
  if (lm == 0) {
#pragma unroll
    for (int i = 0; i < 4; i++)
#pragma unroll
      for (int rr = 0; rr < 4; rr++)
        ssred[(wm + i * 16 + ko * 4 + rr) * 2 + (w & 1)] = rmax[i][rr];
  }
  __syncthreads();
  if (t < 128)
    tilemax[(size_t)ct * BATCH + m0 + t] = fmaxf(ssred[t * 2], ssred[t * 2 + 1]);
}

// ---------------------------------------------------------------------------
// K2b: transpose tilemax [tile][row] -> tmaxT [row][tile]
// ---------------------------------------------------------------------------
__global__ __launch_bounds__(256) void k_tmt(const float* __restrict__ in,
                                             float* __restrict__ outT) {
  __shared__ float tile[32][33];
  int T0 = blockIdx.x * 32, r0 = blockIdx.y * 32;
  int tx = threadIdx.x & 31, ty = threadIdx.x >> 5;
#pragma unroll
  for (int i = 0; i < 32; i += 8) {
    int T = T0 + ty + i;
    if (T < NTILE) tile[ty + i][tx] = in[(size_t)T * BATCH + r0 + tx];
  }
  __syncthreads();
#pragma unroll
  for (int i = 0; i < 32; i += 8) {
    int r = r0 + ty + i;
    int T = T0 + tx;
    if (T < NTILE) outT[(size_t)r * NTILE + T] = tile[tx][ty + i];
  }
}

// ---------------------------------------------------------------------------
// K3: exact fp32 target cosine, intra_scores, angular-margin logit at y[b]
// ---------------------------------------------------------------------------
__global__ __launch_bounds__(256) void k_fix(const float* __restrict__ x,
                                             const float* __restrict__ W,
                                             const int* __restrict__ yraw,
                                             const int* __restrict__ yflag,
                                             const float* __restrict__ invx,
                                             float* __restrict__ out) {
  int b = blockIdx.x, t = threadIdx.x;
  int cls = (*yflag) ? yraw[2 * b] : yraw[b];
  __shared__ float rd[256], rs[256];
  float dot = 0.f, ssw = 0.f;
#pragma unroll
  for (int h = 0; h < 2; h++) {
    int k   = t + h * 256;
    float xv = x[b * IN_DIM + k];
    float wv = W[(size_t)k * NCLS + cls];
    dot += xv * wv;
    ssw += wv * wv;
  }
  rd[t] = dot; rs[t] = ssw;
  __syncthreads();
  for (int s = 128; s > 0; s >>= 1) {
    if (t < s) { rd[t] += rd[t + s]; rs[t] += rs[t + s]; }
    __syncthreads();
  }
  if (t == 0) {
    float iw  = 1.0f / fmaxf(sqrtf(rs[0]), 1e-12f);
    float tgt = rd[0] * invx[b] * iw;
    tgt = fminf(fmaxf(tgt, -1.f), 1.f);
    out[(size_t)BATCH * NCLS + b] = tgt;  // intra_scores
    const float cosM = 0.87758256189037271612f;   // cos(0.5)
    const float sinM = 0.47942553860420300027f;   // sin(0.5)
    float mc;
    if (tgt > -cosM)   // theta < pi - M
      mc = tgt * cosM - sqrtf(fmaxf(1.f - tgt * tgt, 0.f)) * sinM;
    else
      mc = tgt - sinM * 0.5f;
    out[(size_t)b * NCLS + cls] = 64.f * mc;
  }
}

// ---------------------------------------------------------------------------
// K4: pruned top-10 per row using per-tile maxes (tmaxT layout [row][tile]).
// ---------------------------------------------------------------------------
__global__ __launch_bounds__(256) void k_topk(const float* __restrict__ logits,
                                              const float* __restrict__ tmaxT,
                                              const int* __restrict__ yraw,
                                              const int* __restrict__ yflag,
                                              float* __restrict__ outIdx) {
  const int b = blockIdx.x, t = threadIdx.x;
  const int cls = (*yflag) ? yraw[2 * b] : yraw[b];
  const float* tm = tmaxT + (size_t)b * NTILE;

  __shared__ float lv[2560];
  __shared__ int   li[2560];
  __shared__ float cv[256];
  __shared__ int   ci[256];
  __shared__ int   cp[256];
  __shared__ int   list[NTILE];
  __shared__ int   cnt;
  __shared__ float stau;

  float vals[10]; int idxs[10];
#pragma unroll
  for (int i = 0; i < 10; i++) { vals[i] = -3.402823466e38f; idxs[i] = 0x7fffffff; }

  for (int T = t; T < NTILE; T += 256) {
    float v = tm[T];
    if (v > vals[9] || (v == vals[9] && T < idxs[9])) {
      float cv2 = v; int ci2 = T;
#pragma unroll
      for (int p = 0; p < 10; p++) {
        bool better = (cv2 > vals[p]) || (cv2 == vals[p] && ci2 < idxs[p]);
        if (better) {
          float tv = vals[p]; int ti = idxs[p];
          vals[p] = cv2; idxs[p] = ci2;
          cv2 = tv; ci2 = ti;
        }
      }
    }
  }
#pragma unroll
  for (int i = 0; i < 10; i++) { lv[t * 10 + i] = vals[i]; li[t * 10 + i] = idxs[i]; }
  if (t == 0) cnt = 0;
  __syncthreads();

  for (int r = 0; r < NC; r++) {
    float bv = -3.402823466e38f; int bi = 0x7fffffff; int bp = -1;
#pragma unroll
    for (int i = 0; i < 10; i++) {
      int e = t * 10 + i;
      float v = lv[e];
      if (v > bv || (v == bv && li[e] < bi)) { bv = v; bi = li[e]; bp = e; }
    }
    cv[t] = bv; ci[t] = bi; cp[t] = bp;
    __syncthreads();
    for (int s = 128; s > 0; s >>= 1) {
      if (t < s) {
        if (cv[t + s] > cv[t] || (cv[t + s] == cv[t] && ci[t + s] < ci[t])) {
          cv[t] = cv[t + s]; ci[t] = ci[t + s]; cp[t] = cp[t + s];
        }
      }
      __syncthreads();
    }
    if (t == 0) {
      lv[cp[0]] = -3.402823466e38f;
      if (r == NC - 1) stau = cv[0];
    }
    __syncthreads();
  }
  const float tau = stau;

  for (int T = t; T < NTILE; T += 256)
    if (tm[T] >= tau) { int p = atomicAdd(&cnt, 1); list[p] = T; }
  __syncthreads();
  const int n = cnt;

#pragma unroll
  for (int i = 0; i < 10; i++) { vals[i] = -3.402823466e38f; idxs[i] = 0x7fffffff; }
  const float* row = logits + (size_t)b * NCLS;
  for (int kk = t; kk < n * 128; kk += 256) {
    int T = list[kk >> 7];
    int c = T * 128 + (kk & 127);
    if (c >= NCLS || c == cls) continue;
    float v = row[c];
    if (v > vals[9] || (v == vals[9] && c < idxs[9])) {
      float cv2 = v; int ci2 = c;
#pragma unroll
      for (int p = 0; p < 10; p++) {
        bool better = (cv2 > vals[p]) || (cv2 == vals[p] && ci2 < idxs[p]);
        if (better) {
          float tv = vals[p]; int ti = idxs[p];
          vals[p] = cv2; idxs[p] = ci2;
          cv2 = tv; ci2 = ti;
        }
      }
    }
  }
#pragma unroll
  for (int i = 0; i < 10; i++) { lv[t * 10 + i] = vals[i]; li[t * 10 + i] = idxs[i]; }
  __syncthreads();

  for (int r = 0; r < NC; r++) {
    float bv = -3.402823466e38f; int bi = 0x7fffffff; int bp = -1;
#pragma unroll
    for (int i = 0; i < 10; i++) {
      int e = t * 10 + i;
      float v = lv[e];
      if (v > bv || (v == bv && li[e] < bi)) { bv = v; bi = li[e]; bp = e; }
    }
    cv[t] = bv; ci[t] = bi; cp[t] = bp;
    __syncthreads();
    for (int s = 128; s > 0; s >>= 1) {
      if (t < s) {
        if (cv[t + s] > cv[t] || (cv[t + s] == cv[t] && ci[t + s] < ci[t])) {
          cv[t] = cv[t + s]; ci[t] = ci[t + s]; cp[t] = cp[t + s];
        }
      }
      __syncthreads();
    }
    if (t == 0) {
      outIdx[b * NC + r] = (float)ci[0];
      lv[cp[0]] = -3.402823466e38f;
    }
    __syncthreads();
  }
}

// ---------------------------------------------------------------------------
extern "C" void kernel_launch(void* const* d_in, const int* in_sizes, int n_in,
                              void* d_out, int out_size, void* d_ws, size_t ws_size,
                              hipStream_t stream) {
  const float* x = (const float*)d_in[0];
  const float* W = (const float*)d_in[1];
  const int*   y = (const int*)d_in[2];
  float* out = (float*)d_out;
  char*  ws  = (char*)d_ws;

  _Float16*       xhi  = (_Float16*)ws;                       // 512 KB
  _Float16*       xlo  = (_Float16*)(ws + (1 << 19));         // 512 KB
  float*          invx = (float*)(ws + (1 << 20));            // 2 KB
  int*            yfl  = (int*)(ws + (1 << 20) + 4096);       // 4 B
  float*          invw = (float*)(ws + (1 << 20) + 8192);     // 100096*4 = 392 KB
  float*          tmax = (float*)(ws + (2 << 20));            // 782*512*4 = 1.53 MB
  float*          tmxT = (float*)(ws + (4 << 20));            // 512*782*4 = 1.53 MB
  unsigned short* WhiT = (unsigned short*)(ws + ((size_t)8 << 20));    // 102.5 MB
  unsigned short* WloT = (unsigned short*)(ws + ((size_t)112 << 20));  // 102.5 MB
  const size_t WS_NEED = ((size_t)112 << 20) + (size_t)NCPAD * IN_DIM * 2;

  k_prep<<<BATCH, 256, 0, stream>>>(x, y, xhi, xlo, invx, yfl);
  if (ws_size >= WS_NEED) {
    k_wsplit<<<NCPAD / 64, 256, 0, stream>>>(W, WhiT, WloT, invw);
    k_gemm_fast<<<dim3(8 * 391), 256, 0, stream>>>(xhi, xlo, WhiT, WloT, invx, invw,
                                                   y, yfl, tmax, out);
  } else {
    k_gemm_fb<<<dim3(8 * 391), 256, 0, stream>>>(xhi, xlo, W, invx, y, yfl, tmax, out);
  }
  k_tmt<<<dim3(25, 16), 256, 0, stream>>>(tmax, tmxT);
  k_fix<<<BATCH, 256, 0, stream>>>(x, W, y, yfl, invx, out);
  k_topk<<<BATCH, 256, 0, stream>>>(out, tmxT, y, yfl, out + (size_t)BATCH * NCLS + BATCH);
}